// Round 4
// baseline (472.479 us; speedup 1.0000x reference)
//
#include <hip/hip_runtime.h>

// Shapes (fixed by the problem)
#define LL 192
#define FF 2048

typedef __attribute__((__ext_vector_type__(8)))  __bf16 bf16x8;
typedef __attribute__((__ext_vector_type__(4)))  __bf16 bf16x4;
typedef __attribute__((__ext_vector_type__(4)))  float  f32x4;

#define MFMA16(a, b, c) __builtin_amdgcn_mfma_f32_16x16x32_bf16((a), (b), (c), 0, 0, 0)

// ---------------------------------------------------------------------------
// A0: prep — sig_frag16 in 16x16 MFMA-C register order, bf16 fc0_w / fc2_w,
//     combined per-ff constants for the fused MLP epilogue.
// sig_frag16 idx = ((stile*12 + jtile)*64 + lane)*4 + r holds sigmoid(se[s][t])
//   with s = stile*16 + (lane>>4)*4 + r, t = jtile*16 + (lane&15)
// (mfma_f32_16x16x32 C/D: col = lane&15, row = (lane>>4)*4 + reg)
// ---------------------------------------------------------------------------
__global__ void prep_kernel(const float* __restrict__ se,
                            const float* __restrict__ fc0w,
                            const float* __restrict__ fc2w,
                            const float* __restrict__ fc2b,
                            const float* __restrict__ bn2g,
                            const float* __restrict__ bn2b,
                            const float* __restrict__ fc3w,
                            __bf16* __restrict__ sig16,
                            __bf16* __restrict__ fc0w_bf,
                            __bf16* __restrict__ fc2w_bf,
                            float* __restrict__ h2,
                            float* __restrict__ bb2,
                            float* __restrict__ f3)
{
    int i0 = blockIdx.x * blockDim.x + threadIdx.x;
    int stride = gridDim.x * blockDim.x;
    const float c1 = rsqrtf(1.f + 1e-5f);
    for (int i = i0; i < LL * LL; i += stride) {
        int r = i & 3, lane = (i >> 2) & 63, tile = i >> 8;
        int jt = tile % 12, st = tile / 12;
        int s = st * 16 + (lane >> 4) * 4 + r;
        int t = jt * 16 + (lane & 15);
        sig16[i] = (__bf16)(1.f / (1.f + __expf(-se[s * 192 + t])));
    }
    for (int i = i0; i < 128 * 128; i += stride)
        fc0w_bf[i] = (__bf16)fc0w[i];
    for (int i = i0; i < FF * LL; i += stride)
        fc2w_bf[i] = (__bf16)fc2w[i];
    for (int i = i0; i < FF; i += stride) {
        float h = bn2g[i] * c1;
        h2[i]  = h;
        bb2[i] = fc2b[i] * h + bn2b[i];
        f3[i]  = fc3w[i];
    }
}

// ---------------------------------------------------------------------------
// A1: projection y = X @ fc0_w^T + fc0_b.
//   bx < 384 : query rows -> qfrag16, B-operand fragment order for 16x16x32:
//     addr = q*24576 + (((t>>4)*4 + (d>>5))*64 + ((d>>3)&3)*16 + (t&15))*8 + (d&7)
//   bx >= 384: key rows -> kfeat row-major [24576][128]
// ---------------------------------------------------------------------------
__launch_bounds__(256, 2)
__global__ void qkproj_kernel(const float* __restrict__ qf,
                              const float* __restrict__ gf,
                              const __bf16* __restrict__ w_bf,
                              const float* __restrict__ bias,
                              __bf16* __restrict__ kfeat,
                              __bf16* __restrict__ qfrag16)
{
    __shared__ __bf16 Xs[32][136];
    __shared__ __bf16 Ws[128][136];
    int bx = blockIdx.x, tid = threadIdx.x;
    const float* src = (bx < 384) ? (qf + (size_t)bx * (32 * 128))
                                  : (gf + (size_t)(bx - 384) * (32 * 128));
#pragma unroll
    for (int it = 0; it < 4; ++it) {
        int e = (it * 256 + tid) * 4;
        int r = e >> 7, c = e & 127;
        float4 v = *reinterpret_cast<const float4*>(src + e);
        bf16x4 xv;
        xv[0] = (__bf16)v.x; xv[1] = (__bf16)v.y;
        xv[2] = (__bf16)v.z; xv[3] = (__bf16)v.w;
        *reinterpret_cast<bf16x4*>(&Xs[r][c]) = xv;
    }
#pragma unroll
    for (int it = 0; it < 8; ++it) {
        int e = (it * 256 + tid) * 8;
        int r = e >> 7, c = e & 127;
        *reinterpret_cast<bf16x8*>(&Ws[r][c]) =
            *reinterpret_cast<const bf16x8*>(w_bf + e);
    }
    __syncthreads();

    int wv = tid >> 6, lane = tid & 63, quad = lane >> 4, l16 = lane & 15;
    int n0 = wv * 32;
    f32x4 acc[2][2];
#pragma unroll
    for (int m = 0; m < 2; ++m)
#pragma unroll
        for (int n = 0; n < 2; ++n) acc[m][n] = (f32x4){0.f, 0.f, 0.f, 0.f};
#pragma unroll
    for (int ks = 0; ks < 4; ++ks) {
        bf16x8 a0 = *reinterpret_cast<const bf16x8*>(&Xs[l16][ks * 32 + quad * 8]);
        bf16x8 a1 = *reinterpret_cast<const bf16x8*>(&Xs[16 + l16][ks * 32 + quad * 8]);
        bf16x8 b0 = *reinterpret_cast<const bf16x8*>(&Ws[n0 + l16][ks * 32 + quad * 8]);
        bf16x8 b1 = *reinterpret_cast<const bf16x8*>(&Ws[n0 + 16 + l16][ks * 32 + quad * 8]);
        acc[0][0] = MFMA16(a0, b0, acc[0][0]);
        acc[0][1] = MFMA16(a0, b1, acc[0][1]);
        acc[1][0] = MFMA16(a1, b0, acc[1][0]);
        acc[1][1] = MFMA16(a1, b1, acc[1][1]);
    }
#pragma unroll
    for (int mt = 0; mt < 2; ++mt)
#pragma unroll
        for (int nt = 0; nt < 2; ++nt) {
            int d = n0 + nt * 16 + l16;
            float bv = bias[d];
#pragma unroll
            for (int r = 0; r < 4; ++r) {
                int row = bx * 32 + mt * 16 + quad * 4 + r;
                __bf16 val = (__bf16)(acc[mt][nt][r] + bv);
                if (bx < 384) {
                    int qi = row / 192, tl = row % 192;
                    int addr = qi * 24576 +
                        (((tl >> 4) * 4 + (d >> 5)) * 64 +
                         ((d >> 3) & 3) * 16 + (tl & 15)) * 8 + (d & 7);
                    qfrag16[addr] = val;
                } else {
                    int rk = row - 12288;
                    kfeat[(size_t)rk * 128 + d] = val;
                }
            }
        }
}

// ---------------------------------------------------------------------------
// B: per-pair score GEMM + sigmoid-modulation + dual max-reduce (dominant).
//    256 threads = 4 waves. Per 2-pair group: 12 supertiles (3 sg x 2 jg x 2 pp),
//    wave w takes slots {w, w+4, w+8} (jg = w&1 fixed).  Supertile = 64s x 96t
//    = acc[4][6] f32x4 (96 VGPRs).  A (key rows) from L2 coalesced, B (query)
//    from LDS fragment order (conflict-free b128), sig from sig16 in C-reg order.
//    Epilogue: per-lane rm[4] = 4 consecutive s -> ONE ds_write_b64 per i-tile
//    into transposed rowT (no shuffles); colmax via 2 shuffles/j.
//    LDS 77.8 KB -> 2 independent blocks/CU.
// ---------------------------------------------------------------------------
__launch_bounds__(256, 2)
__global__ void score_kernel(const __bf16* __restrict__ kfeat,
                             const __bf16* __restrict__ qfrag16,
                             const __bf16* __restrict__ sig16,
                             const float* __restrict__ bn1g,
                             const float* __restrict__ bn1b,
                             __bf16* __restrict__ Sred)
{
    __shared__ __bf16 qf[24576];           // 49,152 B  (Q fragments)
    __shared__ __bf16 rowT[2][32][200];    // 25,600 B  (per-class partial row maxes)
    __shared__ __bf16 colmax[2][192][4];   //  3,072 B  (per-t maxes, 3 sg slots)

    int tid = threadIdx.x;
    int q = blockIdx.x & 63;
    int kbase = (blockIdx.x >> 6) << 3;    // kg-major: kfeat L2 locality
    int w = tid >> 6, lane = tid & 63, quad = lane >> 4, l16 = lane & 15;

    const __bf16* qsrc = qfrag16 + (size_t)q * 24576;
#pragma unroll
    for (int it = 0; it < 12; ++it) {
        int e = (it * 256 + tid) * 8;
        *reinterpret_cast<bf16x8*>(&qf[e]) =
            *reinterpret_cast<const bf16x8*>(qsrc + e);
    }
    const float g1c = bn1g[0] * rsqrtf(1.f + 1e-5f);
    const float b1v = bn1b[0];
    __syncthreads();

    for (int kg = 0; kg < 4; ++kg) {       // 2 pairs per group
#pragma unroll
        for (int u = 0; u < 3; ++u) {
            int slot = w + 4 * u;          // 0..11
            int pp = (slot >= 6) ? 1 : 0;
            int idx = slot - 6 * pp;
            int sg = idx >> 1, jg = idx & 1;
            int kidx = kbase + 2 * kg + pp;
            const __bf16* kp = kfeat + (size_t)kidx * 24576 +
                               (64 * sg + l16) * 128 + quad * 8;

            f32x4 acc[4][6];
#pragma unroll
            for (int i = 0; i < 4; ++i)
#pragma unroll
                for (int j = 0; j < 6; ++j) acc[i][j] = (f32x4){0.f, 0.f, 0.f, 0.f};

#pragma unroll
            for (int ks = 0; ks < 4; ++ks) {
                bf16x8 a[4];
#pragma unroll
                for (int i = 0; i < 4; ++i)
                    a[i] = *reinterpret_cast<const bf16x8*>(kp + i * (16 * 128) + ks * 32);
#pragma unroll
                for (int j = 0; j < 6; ++j) {
                    bf16x8 b = *reinterpret_cast<const bf16x8*>(
                        &qf[((jg * 6 + j) * 4 + ks) * 512 + lane * 8]);
#pragma unroll
                    for (int i = 0; i < 4; ++i)
                        acc[i][j] = MFMA16(a[i], b, acc[i][j]);
                }
            }

            // Epilogue: v = acc * sig;  s = 64sg+16i+quad*4+r, t = (jg*6+j)*16+l16
            float cm[6];
#pragma unroll
            for (int j = 0; j < 6; ++j) cm[j] = -3.0e38f;
#pragma unroll
            for (int i = 0; i < 4; ++i) {
                int stile = sg * 4 + i;
                float rm0 = -3.0e38f, rm1 = -3.0e38f, rm2 = -3.0e38f, rm3 = -3.0e38f;
#pragma unroll
                for (int j = 0; j < 6; ++j) {
                    bf16x4 sgv = *reinterpret_cast<const bf16x4*>(
                        sig16 + ((size_t)(stile * 12 + jg * 6 + j) * 64 + lane) * 4);
                    float v0 = acc[i][j][0] * (float)sgv[0];
                    float v1 = acc[i][j][1] * (float)sgv[1];
                    float v2 = acc[i][j][2] * (float)sgv[2];
                    float v3 = acc[i][j][3] * (float)sgv[3];
                    rm0 = fmaxf(rm0, v0); rm1 = fmaxf(rm1, v1);
                    rm2 = fmaxf(rm2, v2); rm3 = fmaxf(rm3, v3);
                    cm[j] = fmaxf(cm[j], fmaxf(fmaxf(v0, v1), fmaxf(v2, v3)));
                }
                bf16x4 pk;
                pk[0] = (__bf16)rm0; pk[1] = (__bf16)rm1;
                pk[2] = (__bf16)rm2; pk[3] = (__bf16)rm3;
                *reinterpret_cast<bf16x4*>(
                    &rowT[pp][jg * 16 + l16][64 * sg + 16 * i + quad * 4]) = pk;
            }
#pragma unroll
            for (int j = 0; j < 6; ++j) {
                cm[j] = fmaxf(cm[j], __shfl_xor(cm[j], 16, 64));
                cm[j] = fmaxf(cm[j], __shfl_xor(cm[j], 32, 64));
            }
            if (quad == 0) {
#pragma unroll
                for (int j = 0; j < 6; ++j)
                    colmax[pp][(jg * 6 + j) * 16 + l16][sg] = (__bf16)cm[j];
            }
        }
        __syncthreads();   // all 12 supertiles of both pairs done

#pragma unroll
        for (int pp = 0; pp < 2; ++pp) {
            if (tid < 192) {
                int kidx = kbase + 2 * kg + pp;
                size_t pb = (size_t)(q * 128 + kidx) * 384;
                // row 2p: max over s, indexed by t
                float m0 = (float)colmax[pp][tid][0];
                m0 = fmaxf(m0, (float)colmax[pp][tid][1]);
                m0 = fmaxf(m0, (float)colmax[pp][tid][2]);
                Sred[pb + tid] = (__bf16)(m0 * g1c + b1v);
                // row 2p+1: max over t, indexed by s
                float m1 = -3.0e38f;
#pragma unroll
                for (int c = 0; c < 32; ++c)
                    m1 = fmaxf(m1, (float)rowT[pp][c][tid]);
                Sred[pb + 192 + tid] = (__bf16)(m1 * g1c + b1v);
            }
        }
        __syncthreads();   // rowT/colmax free for next group
    }
}

// ---------------------------------------------------------------------------
// C: fused fc2 + bn2 + relu + fc3 + pair-sum + bn3.  64 Sred rows per block,
//    8 waves x 256 ff-cols each, fc3 dot accumulated inline.
// ---------------------------------------------------------------------------
__launch_bounds__(512, 2)
__global__ void mlp_kernel(const __bf16* __restrict__ Sred,
                           const __bf16* __restrict__ fc2w_bf,
                           const float* __restrict__ h2,
                           const float* __restrict__ bb2,
                           const float* __restrict__ f3,
                           const float* __restrict__ fc3b,
                           const float* __restrict__ bn3g,
                           const float* __restrict__ bn3b,
                           float* __restrict__ out)
{
    __shared__ __bf16 As[64][200];
    __shared__ float  psum_lds[8][64];
    int bx = blockIdx.x, tid = threadIdx.x;
    const __bf16* asrc = Sred + (size_t)bx * (64 * 192);
#pragma unroll
    for (int it = 0; it < 3; ++it) {
        int e = (it * 512 + tid) * 8;
        int r = e / 192, c = e - r * 192;
        *reinterpret_cast<bf16x8*>(&As[r][c]) =
            *reinterpret_cast<const bf16x8*>(asrc + e);
    }
    __syncthreads();

    int wv = tid >> 6, lane = tid & 63, quad = lane >> 4, l16 = lane & 15;
    bf16x8 af[4][6];
#pragma unroll
    for (int m = 0; m < 4; ++m)
#pragma unroll
        for (int kk = 0; kk < 6; ++kk)
            af[m][kk] = *reinterpret_cast<const bf16x8*>(
                &As[m * 16 + l16][kk * 32 + quad * 8]);

    float ps[4][4] = {{0.f,0.f,0.f,0.f},{0.f,0.f,0.f,0.f},
                      {0.f,0.f,0.f,0.f},{0.f,0.f,0.f,0.f}};
    for (int nt = 0; nt < 16; ++nt) {
        int n0 = wv * 256 + nt * 16;
        f32x4 acc[4];
#pragma unroll
        for (int m = 0; m < 4; ++m) acc[m] = (f32x4){0.f, 0.f, 0.f, 0.f};
        const __bf16* bp = fc2w_bf + (size_t)(n0 + l16) * 192 + quad * 8;
#pragma unroll
        for (int kk = 0; kk < 6; ++kk) {
            bf16x8 b = *reinterpret_cast<const bf16x8*>(bp + kk * 32);
#pragma unroll
            for (int m = 0; m < 4; ++m) acc[m] = MFMA16(af[m][kk], b, acc[m]);
        }
        int n = n0 + l16;
        float hh = h2[n], bb = bb2[n], ffv = f3[n];
#pragma unroll
        for (int m = 0; m < 4; ++m)
#pragma unroll
            for (int r = 0; r < 4; ++r)
                ps[m][r] += fmaxf(acc[m][r] * hh + bb, 0.f) * ffv;
    }
#pragma unroll
    for (int m = 0; m < 4; ++m)
#pragma unroll
        for (int r = 0; r < 4; ++r) {
            float v = ps[m][r];
            v += __shfl_xor(v, 1, 64);
            v += __shfl_xor(v, 2, 64);
            v += __shfl_xor(v, 4, 64);
            v += __shfl_xor(v, 8, 64);
            if (l16 == 0) psum_lds[wv][m * 16 + quad * 4 + r] = v;
        }
    __syncthreads();
    if (tid < 32) {
        float s = 0.f;
#pragma unroll
        for (int w = 0; w < 8; ++w)
            s += psum_lds[w][2 * tid] + psum_lds[w][2 * tid + 1];
        const float c1 = rsqrtf(1.f + 1e-5f);
        out[bx * 32 + tid] = (s + 2.f * fc3b[0]) * (bn3g[0] * c1) + bn3b[0];
    }
}

// ---------------------------------------------------------------------------
extern "C" void kernel_launch(void* const* d_in, const int* in_sizes, int n_in,
                              void* d_out, int out_size, void* d_ws, size_t ws_size,
                              hipStream_t stream)
{
    const float* q_feat = (const float*)d_in[0];
    const float* g_feat = (const float*)d_in[1];
    const float* se     = (const float*)d_in[2];
    const float* fc0w   = (const float*)d_in[3];
    const float* fc0b   = (const float*)d_in[4];
    const float* fc2w   = (const float*)d_in[5];
    const float* fc2b   = (const float*)d_in[6];
    const float* fc3w   = (const float*)d_in[7];
    const float* fc3b   = (const float*)d_in[8];
    const float* bn1g   = (const float*)d_in[9];
    const float* bn1b   = (const float*)d_in[10];
    const float* bn2g   = (const float*)d_in[11];
    const float* bn2b   = (const float*)d_in[12];
    const float* bn3g   = (const float*)d_in[13];
    const float* bn3b   = (const float*)d_in[14];
    float* out = (float*)d_out;

    char* ws = (char*)d_ws;
    __bf16* kfeat    = (__bf16*)(ws);                 //  6,291,456 B
    __bf16* qfrag16  = (__bf16*)(ws +  6291456);      //  3,145,728 B
    __bf16* sig16    = (__bf16*)(ws +  9437184);      //     73,728 B
    __bf16* fc0w_bf  = (__bf16*)(ws +  9510912);      //     32,768 B
    __bf16* fc2w_bf  = (__bf16*)(ws +  9543680);      //    786,432 B
    float*  h2       = (float*) (ws + 10330112);      //      8,192 B
    float*  bb2      = (float*) (ws + 10338304);      //      8,192 B
    float*  f3       = (float*) (ws + 10346496);      //      8,192 B
    __bf16* Sred     = (__bf16*)(ws + 10354688);      //  6,291,456 B (16.65 MB total)

    prep_kernel<<<256, 256, 0, stream>>>(se, fc0w, fc2w, fc2b, bn2g, bn2b, fc3w,
                                         sig16, fc0w_bf, fc2w_bf, h2, bb2, f3);
    qkproj_kernel<<<1152, 256, 0, stream>>>(q_feat, g_feat, fc0w_bf, fc0b,
                                            kfeat, qfrag16);
    score_kernel<<<1024, 256, 0, stream>>>(kfeat, qfrag16, sig16, bn1g, bn1b, Sred);
    mlp_kernel<<<256, 512, 0, stream>>>(Sred, fc2w_bf, h2, bb2, f3,
                                        fc3b, bn3g, bn3b, out);
}

// Round 5
// 308.935 us; speedup vs baseline: 1.5294x; 1.5294x over previous
//
#include <hip/hip_runtime.h>

// Shapes (fixed by the problem)
#define LL 192
#define FF 2048

typedef __attribute__((__ext_vector_type__(8)))  __bf16 bf16x8;
typedef __attribute__((__ext_vector_type__(4)))  __bf16 bf16x4;
typedef __attribute__((__ext_vector_type__(4)))  float  f32x4;

#define MFMA16(a, b, c) __builtin_amdgcn_mfma_f32_16x16x32_bf16((a), (b), (c), 0, 0, 0)

// Empirical gfx950 law (R1-R4 evidence): VGPR budget ~= 256 / (launch_bounds 2nd arg).
// Use (256,1) for register-heavy kernels; LDS caps blocks/CU anyway.

// ---------------------------------------------------------------------------
// A0: prep — sig16 in 16x16 MFMA-C register order, bf16 fc2_w / fc0_w,
//     combined per-ff constants for the fused MLP epilogue.
// sig16 idx = ((stile*12 + jtile)*64 + lane)*4 + r holds sigmoid(se[s][t])
//   with s = stile*16 + (lane>>4)*4 + r, t = jtile*16 + (lane&15)
// ---------------------------------------------------------------------------
__global__ void prep_kernel(const float* __restrict__ se,
                            const float* __restrict__ fc0w,
                            const float* __restrict__ fc2w,
                            const float* __restrict__ fc2b,
                            const float* __restrict__ bn2g,
                            const float* __restrict__ bn2b,
                            const float* __restrict__ fc3w,
                            __bf16* __restrict__ sig16,
                            __bf16* __restrict__ fc0w_bf,
                            __bf16* __restrict__ fc2w_bf,
                            float* __restrict__ h2,
                            float* __restrict__ bb2,
                            float* __restrict__ f3)
{
    int i0 = blockIdx.x * blockDim.x + threadIdx.x;
    int stride = gridDim.x * blockDim.x;
    const float c1 = rsqrtf(1.f + 1e-5f);
    for (int i = i0; i < LL * LL; i += stride) {
        int r = i & 3, lane = (i >> 2) & 63, tile = i >> 8;
        int jt = tile % 12, st = tile / 12;
        int s = st * 16 + (lane >> 4) * 4 + r;
        int t = jt * 16 + (lane & 15);
        sig16[i] = (__bf16)(1.f / (1.f + __expf(-se[s * 192 + t])));
    }
    for (int i = i0; i < 128 * 128; i += stride)
        fc0w_bf[i] = (__bf16)fc0w[i];
    for (int i = i0; i < FF * LL; i += stride)
        fc2w_bf[i] = (__bf16)fc2w[i];
    for (int i = i0; i < FF; i += stride) {
        float h = bn2g[i] * c1;
        h2[i]  = h;
        bb2[i] = fc2b[i] * h + bn2b[i];
        f3[i]  = fc3w[i];
    }
}

// ---------------------------------------------------------------------------
// A1: projection y = X @ fc0_w^T + fc0_b, outputs in MFMA fragment order.
//   Both q and k outputs use the SAME per-16-row-group layout:
//     group base = (row/192)*24576 + ((row%192)>>4)*2048
//     in-group   = (d>>5)*512 + ((d>>3)&3)*128 + (row&15)*8 + (d&7)
//   For q rows this is the 16x16x32 B-operand order (t on lane&15);
//   for k rows the A-operand order (s on lane&15).  Outputs are staged in
//   LDS then dumped as contiguous bf16x8 (kills the 2-B global scatter).
// ---------------------------------------------------------------------------
__launch_bounds__(256, 2)
__global__ void qkproj_kernel(const float* __restrict__ qf,
                              const float* __restrict__ gf,
                              const __bf16* __restrict__ w_bf,
                              const float* __restrict__ bias,
                              __bf16* __restrict__ kfragA,
                              __bf16* __restrict__ qfrag16)
{
    __shared__ __bf16 Xs[32][136];
    __shared__ __bf16 Ws[128][136];
    __shared__ __bf16 Os[4096];          // 32 rows x 128, fragment order
    int bx = blockIdx.x, tid = threadIdx.x;
    const float* src = (bx < 384) ? (qf + (size_t)bx * (32 * 128))
                                  : (gf + (size_t)(bx - 384) * (32 * 128));
#pragma unroll
    for (int it = 0; it < 4; ++it) {
        int e = (it * 256 + tid) * 4;
        int r = e >> 7, c = e & 127;
        float4 v = *reinterpret_cast<const float4*>(src + e);
        bf16x4 xv;
        xv[0] = (__bf16)v.x; xv[1] = (__bf16)v.y;
        xv[2] = (__bf16)v.z; xv[3] = (__bf16)v.w;
        *reinterpret_cast<bf16x4*>(&Xs[r][c]) = xv;
    }
#pragma unroll
    for (int it = 0; it < 8; ++it) {
        int e = (it * 256 + tid) * 8;
        int r = e >> 7, c = e & 127;
        *reinterpret_cast<bf16x8*>(&Ws[r][c]) =
            *reinterpret_cast<const bf16x8*>(w_bf + e);
    }
    __syncthreads();

    int wv = tid >> 6, lane = tid & 63, quad = lane >> 4, l16 = lane & 15;
    int n0 = wv * 32;
    f32x4 acc[2][2];
#pragma unroll
    for (int m = 0; m < 2; ++m)
#pragma unroll
        for (int n = 0; n < 2; ++n) acc[m][n] = (f32x4){0.f, 0.f, 0.f, 0.f};
#pragma unroll
    for (int ks = 0; ks < 4; ++ks) {
        bf16x8 a0 = *reinterpret_cast<const bf16x8*>(&Xs[l16][ks * 32 + quad * 8]);
        bf16x8 a1 = *reinterpret_cast<const bf16x8*>(&Xs[16 + l16][ks * 32 + quad * 8]);
        bf16x8 b0 = *reinterpret_cast<const bf16x8*>(&Ws[n0 + l16][ks * 32 + quad * 8]);
        bf16x8 b1 = *reinterpret_cast<const bf16x8*>(&Ws[n0 + 16 + l16][ks * 32 + quad * 8]);
        acc[0][0] = MFMA16(a0, b0, acc[0][0]);
        acc[0][1] = MFMA16(a0, b1, acc[0][1]);
        acc[1][0] = MFMA16(a1, b0, acc[1][0]);
        acc[1][1] = MFMA16(a1, b1, acc[1][1]);
    }
    // stage into Os in fragment order: rows are 16-aligned groups (mt), cols d
#pragma unroll
    for (int mt = 0; mt < 2; ++mt)
#pragma unroll
        for (int nt = 0; nt < 2; ++nt) {
            int d = n0 + nt * 16 + l16;
            float bv = bias[d];
            int abase = mt * 2048 + (d >> 5) * 512 + ((d >> 3) & 3) * 128 + (d & 7);
#pragma unroll
            for (int r = 0; r < 4; ++r)
                Os[abase + (quad * 4 + r) * 8] = (__bf16)(acc[mt][nt][r] + bv);
        }
    __syncthreads();

    int row0 = bx * 32;
    __bf16* dst;
    if (bx < 384) {
        int qi = row0 / 192, tg0 = (row0 % 192) >> 4;
        dst = qfrag16 + qi * 24576 + tg0 * 2048;
    } else {
        int rk0 = row0 - 12288;
        int ki = rk0 / 192, sg0 = (rk0 % 192) >> 4;
        dst = kfragA + ki * 24576 + sg0 * 2048;
    }
#pragma unroll
    for (int it = 0; it < 2; ++it) {
        int e = (it * 256 + tid) * 8;
        *reinterpret_cast<bf16x8*>(dst + e) =
            *reinterpret_cast<const bf16x8*>(&Os[e]);
    }
}

// ---------------------------------------------------------------------------
// B: per-pair score GEMM + sigmoid-modulation + dual max-reduce (dominant).
//    256 threads = 4 waves. Per 2-pair group: 12 supertiles (3 sg x 2 jg x 2 pp),
//    wave w takes slots {w, w+4, w+8}.  Supertile = 64s x 96t = acc[4][6] f32x4
//    (96 VGPRs; budget 256 via launch_bounds(256,1) -> NO SPILL).
//    A (key) read from kfragA in fragment order (contiguous 1KB/instr from L2),
//    B (query) from LDS fragment order, sig from sig16 in C-reg order.
//    LDS 77.8 KB -> 2 independent blocks/CU overlap pipes.
// ---------------------------------------------------------------------------
__launch_bounds__(256, 1)
__global__ void score_kernel(const __bf16* __restrict__ kfragA,
                             const __bf16* __restrict__ qfrag16,
                             const __bf16* __restrict__ sig16,
                             const float* __restrict__ bn1g,
                             const float* __restrict__ bn1b,
                             __bf16* __restrict__ Sred)
{
    __shared__ __bf16 qf[24576];           // 49,152 B  (Q fragments)
    __shared__ __bf16 rowT[2][32][200];    // 25,600 B  (per-t-class partial row maxes)
    __shared__ __bf16 colmax[2][192][4];   //  3,072 B  (per-t maxes, 3 sg slots)

    int tid = threadIdx.x;
    int q = blockIdx.x & 63;
    int kbase = (blockIdx.x >> 6) << 3;    // kg-major: kfragA L2 locality
    int w = tid >> 6, lane = tid & 63, quad = lane >> 4, l16 = lane & 15;

    const __bf16* qsrc = qfrag16 + (size_t)q * 24576;
#pragma unroll
    for (int it = 0; it < 12; ++it) {
        int e = (it * 256 + tid) * 8;
        *reinterpret_cast<bf16x8*>(&qf[e]) =
            *reinterpret_cast<const bf16x8*>(qsrc + e);
    }
    const float g1c = bn1g[0] * rsqrtf(1.f + 1e-5f);
    const float b1v = bn1b[0];
    __syncthreads();

    for (int kg = 0; kg < 4; ++kg) {       // 2 pairs per group
#pragma unroll
        for (int u = 0; u < 3; ++u) {
            int slot = w + 4 * u;          // 0..11
            int pp = (slot >= 6) ? 1 : 0;
            int idx = slot - 6 * pp;
            int sg = idx >> 1, jg = idx & 1;
            int kidx = kbase + 2 * kg + pp;
            const __bf16* kp = kfragA + (size_t)kidx * 24576 + lane * 8;

            f32x4 acc[4][6];
#pragma unroll
            for (int i = 0; i < 4; ++i)
#pragma unroll
                for (int j = 0; j < 6; ++j) acc[i][j] = (f32x4){0.f, 0.f, 0.f, 0.f};

#pragma unroll
            for (int ks = 0; ks < 4; ++ks) {
                bf16x8 a[4];
#pragma unroll
                for (int i = 0; i < 4; ++i)
                    a[i] = *reinterpret_cast<const bf16x8*>(
                        kp + ((sg * 4 + i) * 4 + ks) * 512);
#pragma unroll
                for (int j = 0; j < 6; ++j) {
                    bf16x8 b = *reinterpret_cast<const bf16x8*>(
                        &qf[((jg * 6 + j) * 4 + ks) * 512 + lane * 8]);
#pragma unroll
                    for (int i = 0; i < 4; ++i)
                        acc[i][j] = MFMA16(a[i], b, acc[i][j]);
                }
            }

            // Epilogue: v = acc * sig;  s = 64sg+16i+quad*4+r, t = (jg*6+j)*16+l16
            float cm[6];
#pragma unroll
            for (int j = 0; j < 6; ++j) cm[j] = -3.0e38f;
#pragma unroll
            for (int i = 0; i < 4; ++i) {
                int stile = sg * 4 + i;
                float rm0 = -3.0e38f, rm1 = -3.0e38f, rm2 = -3.0e38f, rm3 = -3.0e38f;
#pragma unroll
                for (int j = 0; j < 6; ++j) {
                    bf16x4 sgv = *reinterpret_cast<const bf16x4*>(
                        sig16 + ((size_t)(stile * 12 + jg * 6 + j) * 64 + lane) * 4);
                    float v0 = acc[i][j][0] * (float)sgv[0];
                    float v1 = acc[i][j][1] * (float)sgv[1];
                    float v2 = acc[i][j][2] * (float)sgv[2];
                    float v3 = acc[i][j][3] * (float)sgv[3];
                    rm0 = fmaxf(rm0, v0); rm1 = fmaxf(rm1, v1);
                    rm2 = fmaxf(rm2, v2); rm3 = fmaxf(rm3, v3);
                    cm[j] = fmaxf(cm[j], fmaxf(fmaxf(v0, v1), fmaxf(v2, v3)));
                }
                bf16x4 pk;
                pk[0] = (__bf16)rm0; pk[1] = (__bf16)rm1;
                pk[2] = (__bf16)rm2; pk[3] = (__bf16)rm3;
                *reinterpret_cast<bf16x4*>(
                    &rowT[pp][jg * 16 + l16][64 * sg + 16 * i + quad * 4]) = pk;
            }
#pragma unroll
            for (int j = 0; j < 6; ++j) {
                cm[j] = fmaxf(cm[j], __shfl_xor(cm[j], 16, 64));
                cm[j] = fmaxf(cm[j], __shfl_xor(cm[j], 32, 64));
            }
            if (quad == 0) {
#pragma unroll
                for (int j = 0; j < 6; ++j)
                    colmax[pp][(jg * 6 + j) * 16 + l16][sg] = (__bf16)cm[j];
            }
        }
        __syncthreads();   // all 12 supertiles of both pairs done

#pragma unroll
        for (int pp = 0; pp < 2; ++pp) {
            if (tid < 192) {
                int kidx = kbase + 2 * kg + pp;
                size_t pb = (size_t)(q * 128 + kidx) * 384;
                // row 2p: max over s, indexed by t
                float m0 = (float)colmax[pp][tid][0];
                m0 = fmaxf(m0, (float)colmax[pp][tid][1]);
                m0 = fmaxf(m0, (float)colmax[pp][tid][2]);
                Sred[pb + tid] = (__bf16)(m0 * g1c + b1v);
                // row 2p+1: max over t, indexed by s
                float m1 = -3.0e38f;
#pragma unroll
                for (int c = 0; c < 32; ++c)
                    m1 = fmaxf(m1, (float)rowT[pp][c][tid]);
                Sred[pb + 192 + tid] = (__bf16)(m1 * g1c + b1v);
            }
        }
        __syncthreads();   // rowT/colmax free for next group
    }
}

// ---------------------------------------------------------------------------
// C: fused fc2 + bn2 + relu + fc3 + pair-sum + bn3.  64 Sred rows per block,
//    8 waves x 256 ff-cols each, fc3 dot accumulated inline.
// ---------------------------------------------------------------------------
__launch_bounds__(512, 2)
__global__ void mlp_kernel(const __bf16* __restrict__ Sred,
                           const __bf16* __restrict__ fc2w_bf,
                           const float* __restrict__ h2,
                           const float* __restrict__ bb2,
                           const float* __restrict__ f3,
                           const float* __restrict__ fc3b,
                           const float* __restrict__ bn3g,
                           const float* __restrict__ bn3b,
                           float* __restrict__ out)
{
    __shared__ __bf16 As[64][200];
    __shared__ float  psum_lds[8][64];
    int bx = blockIdx.x, tid = threadIdx.x;
    const __bf16* asrc = Sred + (size_t)bx * (64 * 192);
#pragma unroll
    for (int it = 0; it < 3; ++it) {
        int e = (it * 512 + tid) * 8;
        int r = e / 192, c = e - r * 192;
        *reinterpret_cast<bf16x8*>(&As[r][c]) =
            *reinterpret_cast<const bf16x8*>(asrc + e);
    }
    __syncthreads();

    int wv = tid >> 6, lane = tid & 63, quad = lane >> 4, l16 = lane & 15;
    bf16x8 af[4][6];
#pragma unroll
    for (int m = 0; m < 4; ++m)
#pragma unroll
        for (int kk = 0; kk < 6; ++kk)
            af[m][kk] = *reinterpret_cast<const bf16x8*>(
                &As[m * 16 + l16][kk * 32 + quad * 8]);

    float ps[4][4] = {{0.f,0.f,0.f,0.f},{0.f,0.f,0.f,0.f},
                      {0.f,0.f,0.f,0.f},{0.f,0.f,0.f,0.f}};
    for (int nt = 0; nt < 16; ++nt) {
        int n0 = wv * 256 + nt * 16;
        f32x4 acc[4];
#pragma unroll
        for (int m = 0; m < 4; ++m) acc[m] = (f32x4){0.f, 0.f, 0.f, 0.f};
        const __bf16* bp = fc2w_bf + (size_t)(n0 + l16) * 192 + quad * 8;
#pragma unroll
        for (int kk = 0; kk < 6; ++kk) {
            bf16x8 b = *reinterpret_cast<const bf16x8*>(bp + kk * 32);
#pragma unroll
            for (int m = 0; m < 4; ++m) acc[m] = MFMA16(af[m][kk], b, acc[m]);
        }
        int n = n0 + l16;
        float hh = h2[n], bb = bb2[n], ffv = f3[n];
#pragma unroll
        for (int m = 0; m < 4; ++m)
#pragma unroll
            for (int r = 0; r < 4; ++r)
                ps[m][r] += fmaxf(acc[m][r] * hh + bb, 0.f) * ffv;
    }
#pragma unroll
    for (int m = 0; m < 4; ++m)
#pragma unroll
        for (int r = 0; r < 4; ++r) {
            float v = ps[m][r];
            v += __shfl_xor(v, 1, 64);
            v += __shfl_xor(v, 2, 64);
            v += __shfl_xor(v, 4, 64);
            v += __shfl_xor(v, 8, 64);
            if (l16 == 0) psum_lds[wv][m * 16 + quad * 4 + r] = v;
        }
    __syncthreads();
    if (tid < 32) {
        float s = 0.f;
#pragma unroll
        for (int w = 0; w < 8; ++w)
            s += psum_lds[w][2 * tid] + psum_lds[w][2 * tid + 1];
        const float c1 = rsqrtf(1.f + 1e-5f);
        out[bx * 32 + tid] = (s + 2.f * fc3b[0]) * (bn3g[0] * c1) + bn3b[0];
    }
}

// ---------------------------------------------------------------------------
extern "C" void kernel_launch(void* const* d_in, const int* in_sizes, int n_in,
                              void* d_out, int out_size, void* d_ws, size_t ws_size,
                              hipStream_t stream)
{
    const float* q_feat = (const float*)d_in[0];
    const float* g_feat = (const float*)d_in[1];
    const float* se     = (const float*)d_in[2];
    const float* fc0w   = (const float*)d_in[3];
    const float* fc0b   = (const float*)d_in[4];
    const float* fc2w   = (const float*)d_in[5];
    const float* fc2b   = (const float*)d_in[6];
    const float* fc3w   = (const float*)d_in[7];
    const float* fc3b   = (const float*)d_in[8];
    const float* bn1g   = (const float*)d_in[9];
    const float* bn1b   = (const float*)d_in[10];
    const float* bn2g   = (const float*)d_in[11];
    const float* bn2b   = (const float*)d_in[12];
    const float* bn3g   = (const float*)d_in[13];
    const float* bn3b   = (const float*)d_in[14];
    float* out = (float*)d_out;

    char* ws = (char*)d_ws;
    __bf16* kfragA   = (__bf16*)(ws);                 //  6,291,456 B
    __bf16* qfrag16  = (__bf16*)(ws +  6291456);      //  3,145,728 B
    __bf16* sig16    = (__bf16*)(ws +  9437184);      //     73,728 B
    __bf16* fc0w_bf  = (__bf16*)(ws +  9510912);      //     32,768 B
    __bf16* fc2w_bf  = (__bf16*)(ws +  9543680);      //    786,432 B
    float*  h2       = (float*) (ws + 10330112);      //      8,192 B
    float*  bb2      = (float*) (ws + 10338304);      //      8,192 B
    float*  f3       = (float*) (ws + 10346496);      //      8,192 B
    __bf16* Sred     = (__bf16*)(ws + 10354688);      //  6,291,456 B (16.65 MB total)

    prep_kernel<<<256, 256, 0, stream>>>(se, fc0w, fc2w, fc2b, bn2g, bn2b, fc3w,
                                         sig16, fc0w_bf, fc2w_bf, h2, bb2, f3);
    qkproj_kernel<<<1152, 256, 0, stream>>>(q_feat, g_feat, fc0w_bf, fc0b,
                                            kfragA, qfrag16);
    score_kernel<<<1024, 256, 0, stream>>>(kfragA, qfrag16, sig16, bn1g, bn1b, Sred);
    mlp_kernel<<<256, 512, 0, stream>>>(Sred, fc2w_bf, h2, bb2, f3,
                                        fc3b, bn3g, bn3b, out);
}

// Round 6
// 241.918 us; speedup vs baseline: 1.9531x; 1.2770x over previous
//
#include <hip/hip_runtime.h>

// Shapes (fixed by the problem)
#define LL 192
#define FF 2048

typedef __attribute__((__ext_vector_type__(8)))  __bf16 bf16x8;
typedef __attribute__((__ext_vector_type__(4)))  __bf16 bf16x4;
typedef __attribute__((__ext_vector_type__(4)))  float  f32x4;

#define MFMA16(a, b, c) __builtin_amdgcn_mfma_f32_16x16x32_bf16((a), (b), (c), 0, 0, 0)

// Empirical gfx950 laws (R1-R5 evidence):
//  - VGPR budget ~= 256 / (launch_bounds 2nd arg), any block size.
//  - Resident waves/SIMD steps down at vgpr > {64,128,256} (m69); unified
//    VGPR+AGPR use above ~256 total -> 1 wave/SIMD (R5: 244 regs -> 1 block/CU).
//  => keep register-heavy MFMA kernels at <=128 regs for >=2 waves/SIMD.

// ---------------------------------------------------------------------------
// Kernel 1: fused projection + prep.
//   blocks 0..1151  : y = X @ fc0_w^T + fc0_b -> kfragA / qfrag16 (MFMA
//                     fragment order; fc0_w converted from f32 in-block).
//   blocks 1152..1311: sig16 (16x16 C-reg order), bf16 fc2_w, MLP constants.
// ---------------------------------------------------------------------------
__launch_bounds__(256, 2)
__global__ void proj_prep_kernel(const float* __restrict__ qf_in,
                                 const float* __restrict__ gf_in,
                                 const float* __restrict__ fc0w,
                                 const float* __restrict__ fc0b,
                                 const float* __restrict__ se,
                                 const float* __restrict__ fc2w,
                                 const float* __restrict__ fc2b,
                                 const float* __restrict__ bn2g,
                                 const float* __restrict__ bn2b,
                                 const float* __restrict__ fc3w,
                                 __bf16* __restrict__ kfragA,
                                 __bf16* __restrict__ qfrag16,
                                 __bf16* __restrict__ sig16,
                                 __bf16* __restrict__ fc2w_bf,
                                 float* __restrict__ h2,
                                 float* __restrict__ bb2,
                                 float* __restrict__ f3)
{
    int bx = blockIdx.x, tid = threadIdx.x;
    if (bx >= 1152) {
        // ---- prep part ----
        int i0 = (bx - 1152) * 256 + tid;
        const int stride = 160 * 256;
        const float c1 = rsqrtf(1.f + 1e-5f);
        for (int i = i0; i < LL * LL; i += stride) {
            int r = i & 3, lane = (i >> 2) & 63, tile = i >> 8;
            int jt = tile % 12, st = tile / 12;
            int s = st * 16 + (lane >> 4) * 4 + r;
            int t = jt * 16 + (lane & 15);
            sig16[i] = (__bf16)(1.f / (1.f + __expf(-se[s * 192 + t])));
        }
        for (int i = i0; i < FF * LL; i += stride)
            fc2w_bf[i] = (__bf16)fc2w[i];
        for (int i = i0; i < FF; i += stride) {
            float h = bn2g[i] * c1;
            h2[i]  = h;
            bb2[i] = fc2b[i] * h + bn2b[i];
            f3[i]  = fc3w[i];
        }
        return;
    }
    // ---- projection part ----
    __shared__ __bf16 Xs[32][136];
    __shared__ __bf16 Ws[128][136];
    __shared__ __bf16 Os[4096];          // 32 rows x 128, fragment order
    const float* src = (bx < 384) ? (qf_in + (size_t)bx * (32 * 128))
                                  : (gf_in + (size_t)(bx - 384) * (32 * 128));
#pragma unroll
    for (int it = 0; it < 4; ++it) {
        int e = (it * 256 + tid) * 4;
        int r = e >> 7, c = e & 127;
        float4 v = *reinterpret_cast<const float4*>(src + e);
        bf16x4 xv;
        xv[0] = (__bf16)v.x; xv[1] = (__bf16)v.y;
        xv[2] = (__bf16)v.z; xv[3] = (__bf16)v.w;
        *reinterpret_cast<bf16x4*>(&Xs[r][c]) = xv;
    }
#pragma unroll
    for (int it = 0; it < 16; ++it) {    // fc0_w f32 -> bf16 in LDS
        int e = (it * 256 + tid) * 4;
        int r = e >> 7, c = e & 127;
        float4 v = *reinterpret_cast<const float4*>(fc0w + e);
        bf16x4 xv;
        xv[0] = (__bf16)v.x; xv[1] = (__bf16)v.y;
        xv[2] = (__bf16)v.z; xv[3] = (__bf16)v.w;
        *reinterpret_cast<bf16x4*>(&Ws[r][c]) = xv;
    }
    __syncthreads();

    int wv = tid >> 6, lane = tid & 63, quad = lane >> 4, l16 = lane & 15;
    int n0 = wv * 32;
    f32x4 acc[2][2];
#pragma unroll
    for (int m = 0; m < 2; ++m)
#pragma unroll
        for (int n = 0; n < 2; ++n) acc[m][n] = (f32x4){0.f, 0.f, 0.f, 0.f};
#pragma unroll
    for (int ks = 0; ks < 4; ++ks) {
        bf16x8 a0 = *reinterpret_cast<const bf16x8*>(&Xs[l16][ks * 32 + quad * 8]);
        bf16x8 a1 = *reinterpret_cast<const bf16x8*>(&Xs[16 + l16][ks * 32 + quad * 8]);
        bf16x8 b0 = *reinterpret_cast<const bf16x8*>(&Ws[n0 + l16][ks * 32 + quad * 8]);
        bf16x8 b1 = *reinterpret_cast<const bf16x8*>(&Ws[n0 + 16 + l16][ks * 32 + quad * 8]);
        acc[0][0] = MFMA16(a0, b0, acc[0][0]);
        acc[0][1] = MFMA16(a0, b1, acc[0][1]);
        acc[1][0] = MFMA16(a1, b0, acc[1][0]);
        acc[1][1] = MFMA16(a1, b1, acc[1][1]);
    }
#pragma unroll
    for (int mt = 0; mt < 2; ++mt)
#pragma unroll
        for (int nt = 0; nt < 2; ++nt) {
            int d = n0 + nt * 16 + l16;
            float bv = fc0b[d];
            int abase = mt * 2048 + (d >> 5) * 512 + ((d >> 3) & 3) * 128 + (d & 7);
#pragma unroll
            for (int r = 0; r < 4; ++r)
                Os[abase + (quad * 4 + r) * 8] = (__bf16)(acc[mt][nt][r] + bv);
        }
    __syncthreads();

    int row0 = bx * 32;
    __bf16* dst;
    if (bx < 384) {
        int qi = row0 / 192, tg0 = (row0 % 192) >> 4;
        dst = qfrag16 + qi * 24576 + tg0 * 2048;
    } else {
        int rk0 = row0 - 12288;
        int ki = rk0 / 192, sg0 = (rk0 % 192) >> 4;
        dst = kfragA + ki * 24576 + sg0 * 2048;
    }
#pragma unroll
    for (int it = 0; it < 2; ++it) {
        int e = (it * 256 + tid) * 8;
        *reinterpret_cast<bf16x8*>(dst + e) =
            *reinterpret_cast<const bf16x8*>(&Os[e]);
    }
}

// ---------------------------------------------------------------------------
// Kernel 2: per-pair score GEMM + sigmoid-modulation + dual max-reduce.
//    384 threads = 6 waves; wave w owns s in [32w, 32w+32) x ALL 192 t.
//    sig for the wave's slice = 48 VGPRs, hoisted ONCE per block (fixed
//    across all 8 pairs -> zero sig re-reads).  jg halves processed
//    sequentially with acc[2][6] (48 VGPRs) to stay under the 128-reg cliff.
//    A (key) from L2 in fragment order, B (query) from LDS fragment order.
//    LDS 64.3 KB -> 2 independent blocks/CU = 3 waves/SIMD.
// ---------------------------------------------------------------------------
__launch_bounds__(384, 2)
__global__ void score_kernel(const __bf16* __restrict__ kfragA,
                             const __bf16* __restrict__ qfrag16,
                             const __bf16* __restrict__ sig16,
                             const float* __restrict__ bn1g,
                             const float* __restrict__ bn1b,
                             __bf16* __restrict__ Sred)
{
    __shared__ __bf16 qf[24576];        // 49,152 B  (Q fragments)
    __shared__ __bf16 rowT[32][200];    // 12,800 B  (per-t-class row maxes)
    __shared__ __bf16 colmax[192][6];   //  2,304 B  (per-t maxes, 6 s-slices)

    int tid = threadIdx.x;
    int q = blockIdx.x & 63;
    int kbase = (blockIdx.x >> 6) << 3;
    int w = tid >> 6, lane = tid & 63, quad = lane >> 4, l16 = lane & 15;

    const __bf16* qsrc = qfrag16 + (size_t)q * 24576;
#pragma unroll
    for (int it = 0; it < 8; ++it) {
        int e = (it * 384 + tid) * 8;
        *reinterpret_cast<bf16x8*>(&qf[e]) =
            *reinterpret_cast<const bf16x8*>(qsrc + e);
    }
    const float g1c = bn1g[0] * rsqrtf(1.f + 1e-5f);
    const float b1v = bn1b[0];

    // hoist this wave's sig slice: stiles {2w, 2w+1} x all 12 t-tiles (48 regs)
    bf16x4 sgv[2][12];
#pragma unroll
    for (int i = 0; i < 2; ++i)
#pragma unroll
        for (int jt = 0; jt < 12; ++jt)
            sgv[i][jt] = *reinterpret_cast<const bf16x4*>(
                sig16 + ((size_t)((2 * w + i) * 12 + jt) * 64 + lane) * 4);
    __syncthreads();

    for (int kk = 0; kk < 8; ++kk) {
        int kidx = kbase + kk;
        const __bf16* kp = kfragA + (size_t)kidx * 24576 + lane * 8;
#pragma unroll
        for (int jg = 0; jg < 2; ++jg) {
            f32x4 acc[2][6];
#pragma unroll
            for (int i = 0; i < 2; ++i)
#pragma unroll
                for (int j = 0; j < 6; ++j) acc[i][j] = (f32x4){0.f, 0.f, 0.f, 0.f};

#pragma unroll
            for (int ks = 0; ks < 4; ++ks) {
                bf16x8 a0 = *reinterpret_cast<const bf16x8*>(
                    kp + ((2 * w + 0) * 4 + ks) * 512);
                bf16x8 a1 = *reinterpret_cast<const bf16x8*>(
                    kp + ((2 * w + 1) * 4 + ks) * 512);
#pragma unroll
                for (int j = 0; j < 6; ++j) {
                    bf16x8 b = *reinterpret_cast<const bf16x8*>(
                        &qf[((jg * 6 + j) * 4 + ks) * 512 + lane * 8]);
                    acc[0][j] = MFMA16(a0, b, acc[0][j]);
                    acc[1][j] = MFMA16(a1, b, acc[1][j]);
                }
            }

            // Epilogue: v = acc*sig;  s = 32w+16i+quad*4+r, t = (jg*6+j)*16+l16
            float cm[6];
#pragma unroll
            for (int j = 0; j < 6; ++j) cm[j] = -3.0e38f;
#pragma unroll
            for (int i = 0; i < 2; ++i) {
                float rm0 = -3.0e38f, rm1 = -3.0e38f, rm2 = -3.0e38f, rm3 = -3.0e38f;
#pragma unroll
                for (int j = 0; j < 6; ++j) {
                    bf16x4 sv = sgv[i][jg * 6 + j];
                    float v0 = acc[i][j][0] * (float)sv[0];
                    float v1 = acc[i][j][1] * (float)sv[1];
                    float v2 = acc[i][j][2] * (float)sv[2];
                    float v3 = acc[i][j][3] * (float)sv[3];
                    rm0 = fmaxf(rm0, v0); rm1 = fmaxf(rm1, v1);
                    rm2 = fmaxf(rm2, v2); rm3 = fmaxf(rm3, v3);
                    cm[j] = fmaxf(cm[j], fmaxf(fmaxf(v0, v1), fmaxf(v2, v3)));
                }
                bf16x4 pk;
                pk[0] = (__bf16)rm0; pk[1] = (__bf16)rm1;
                pk[2] = (__bf16)rm2; pk[3] = (__bf16)rm3;
                *reinterpret_cast<bf16x4*>(
                    &rowT[jg * 16 + l16][32 * w + 16 * i + quad * 4]) = pk;
            }
#pragma unroll
            for (int j = 0; j < 6; ++j) {
                cm[j] = fmaxf(cm[j], __shfl_xor(cm[j], 16, 64));
                cm[j] = fmaxf(cm[j], __shfl_xor(cm[j], 32, 64));
            }
            if (quad == 0) {
#pragma unroll
                for (int j = 0; j < 6; ++j)
                    colmax[(jg * 6 + j) * 16 + l16][w] = (__bf16)cm[j];
            }
        }
        __syncthreads();   // rowT/colmax complete for this pair

        if (tid < 192) {
            size_t pb = (size_t)(q * 128 + kidx) * 384;
            // row 2p: max over s, indexed by t
            float m0 = (float)colmax[tid][0];
#pragma unroll
            for (int u = 1; u < 6; ++u) m0 = fmaxf(m0, (float)colmax[tid][u]);
            Sred[pb + tid] = (__bf16)(m0 * g1c + b1v);
            // row 2p+1: max over t, indexed by s
            float m1 = -3.0e38f;
#pragma unroll
            for (int c = 0; c < 32; ++c)
                m1 = fmaxf(m1, (float)rowT[c][tid]);
            Sred[pb + 192 + tid] = (__bf16)(m1 * g1c + b1v);
        }
        __syncthreads();   // arrays free for next pair
    }
}

// ---------------------------------------------------------------------------
// Kernel 3: fused fc2 + bn2 + relu + fc3 + pair-sum + bn3.  64 Sred rows per
//    block, 8 waves x 256 ff-cols.  grid 256 = 1 block/CU, so (512,1) gives
//    the full 256-reg budget (af[4][6]=96 regs hoisted) with zero occupancy
//    cost and no spill.
// ---------------------------------------------------------------------------
__launch_bounds__(512, 1)
__global__ void mlp_kernel(const __bf16* __restrict__ Sred,
                           const __bf16* __restrict__ fc2w_bf,
                           const float* __restrict__ h2,
                           const float* __restrict__ bb2,
                           const float* __restrict__ f3,
                           const float* __restrict__ fc3b,
                           const float* __restrict__ bn3g,
                           const float* __restrict__ bn3b,
                           float* __restrict__ out)
{
    __shared__ __bf16 As[64][200];
    __shared__ float  psum_lds[8][64];
    int bx = blockIdx.x, tid = threadIdx.x;
    const __bf16* asrc = Sred + (size_t)bx * (64 * 192);
#pragma unroll
    for (int it = 0; it < 3; ++it) {
        int e = (it * 512 + tid) * 8;
        int r = e / 192, c = e - r * 192;
        *reinterpret_cast<bf16x8*>(&As[r][c]) =
            *reinterpret_cast<const bf16x8*>(asrc + e);
    }
    __syncthreads();

    int wv = tid >> 6, lane = tid & 63, quad = lane >> 4, l16 = lane & 15;
    bf16x8 af[4][6];
#pragma unroll
    for (int m = 0; m < 4; ++m)
#pragma unroll
        for (int kk = 0; kk < 6; ++kk)
            af[m][kk] = *reinterpret_cast<const bf16x8*>(
                &As[m * 16 + l16][kk * 32 + quad * 8]);

    float ps[4][4] = {{0.f,0.f,0.f,0.f},{0.f,0.f,0.f,0.f},
                      {0.f,0.f,0.f,0.f},{0.f,0.f,0.f,0.f}};
    for (int nt = 0; nt < 16; ++nt) {
        int n0 = wv * 256 + nt * 16;
        f32x4 acc[4];
#pragma unroll
        for (int m = 0; m < 4; ++m) acc[m] = (f32x4){0.f, 0.f, 0.f, 0.f};
        const __bf16* bp = fc2w_bf + (size_t)(n0 + l16) * 192 + quad * 8;
#pragma unroll
        for (int kk = 0; kk < 6; ++kk) {
            bf16x8 b = *reinterpret_cast<const bf16x8*>(bp + kk * 32);
#pragma unroll
            for (int m = 0; m < 4; ++m) acc[m] = MFMA16(af[m][kk], b, acc[m]);
        }
        int n = n0 + l16;
        float hh = h2[n], bb = bb2[n], ffv = f3[n];
#pragma unroll
        for (int m = 0; m < 4; ++m)
#pragma unroll
            for (int r = 0; r < 4; ++r)
                ps[m][r] += fmaxf(acc[m][r] * hh + bb, 0.f) * ffv;
    }
#pragma unroll
    for (int m = 0; m < 4; ++m)
#pragma unroll
        for (int r = 0; r < 4; ++r) {
            float v = ps[m][r];
            v += __shfl_xor(v, 1, 64);
            v += __shfl_xor(v, 2, 64);
            v += __shfl_xor(v, 4, 64);
            v += __shfl_xor(v, 8, 64);
            if (l16 == 0) psum_lds[wv][m * 16 + quad * 4 + r] = v;
        }
    __syncthreads();
    if (tid < 32) {
        float s = 0.f;
#pragma unroll
        for (int w = 0; w < 8; ++w)
            s += psum_lds[w][2 * tid] + psum_lds[w][2 * tid + 1];
        const float c1 = rsqrtf(1.f + 1e-5f);
        out[bx * 32 + tid] = (s + 2.f * fc3b[0]) * (bn3g[0] * c1) + bn3b[0];
    }
}

// ---------------------------------------------------------------------------
extern "C" void kernel_launch(void* const* d_in, const int* in_sizes, int n_in,
                              void* d_out, int out_size, void* d_ws, size_t ws_size,
                              hipStream_t stream)
{
    const float* q_feat = (const float*)d_in[0];
    const float* g_feat = (const float*)d_in[1];
    const float* se     = (const float*)d_in[2];
    const float* fc0w   = (const float*)d_in[3];
    const float* fc0b   = (const float*)d_in[4];
    const float* fc2w   = (const float*)d_in[5];
    const float* fc2b   = (const float*)d_in[6];
    const float* fc3w   = (const float*)d_in[7];
    const float* fc3b   = (const float*)d_in[8];
    const float* bn1g   = (const float*)d_in[9];
    const float* bn1b   = (const float*)d_in[10];
    const float* bn2g   = (const float*)d_in[11];
    const float* bn2b   = (const float*)d_in[12];
    const float* bn3g   = (const float*)d_in[13];
    const float* bn3b   = (const float*)d_in[14];
    float* out = (float*)d_out;

    char* ws = (char*)d_ws;
    __bf16* kfragA   = (__bf16*)(ws);                 //  6,291,456 B
    __bf16* qfrag16  = (__bf16*)(ws +  6291456);      //  3,145,728 B
    __bf16* sig16    = (__bf16*)(ws +  9437184);      //     73,728 B
    __bf16* fc2w_bf  = (__bf16*)(ws +  9543680);      //    786,432 B
    float*  h2       = (float*) (ws + 10330112);      //      8,192 B
    float*  bb2      = (float*) (ws + 10338304);      //      8,192 B
    float*  f3       = (float*) (ws + 10346496);      //      8,192 B
    __bf16* Sred     = (__bf16*)(ws + 10354688);      //  6,291,456 B (16.65 MB total)

    proj_prep_kernel<<<1312, 256, 0, stream>>>(q_feat, g_feat, fc0w, fc0b, se,
                                               fc2w, fc2b, bn2g, bn2b, fc3w,
                                               kfragA, qfrag16, sig16, fc2w_bf,
                                               h2, bb2, f3);
    score_kernel<<<1024, 384, 0, stream>>>(kfragA, qfrag16, sig16, bn1g, bn1b, Sred);
    mlp_kernel<<<256, 512, 0, stream>>>(Sred, fc2w_bf, h2, bb2, f3,
                                        fc3b, bn3g, bn3b, out);
}